// Round 22
// baseline (431.413 us; speedup 1.0000x reference)
//
#include <hip/hip_runtime.h>
#include <hip/hip_bf16.h>
#include <cstdint>
#include <cstddef>

typedef unsigned short u16;
typedef float f32x4 __attribute__((ext_vector_type(4)));
typedef short bf16x8 __attribute__((ext_vector_type(8)));
typedef unsigned short u16x8 __attribute__((ext_vector_type(8)));

__device__ __forceinline__ u16 f2bf(float f) {
    uint32_t u = __float_as_uint(f);
    u += 0x7fffu + ((u >> 16) & 1u);
    return (u16)(u >> 16);
}
__device__ __forceinline__ float bf2f(u16 h) {
    return __uint_as_float(((uint32_t)h) << 16);
}

// sweep-tile swizzle (validated r11)
#define SWZ(c) ((((c) ^ ((c) >> 3)) & 7) << 2)
// k2m-tile swizzle (validated r3)
#define SWZ2(c) ((((c) >> 2) & 7) << 2)

// drain-free barrier: order LDS, keep vmem in flight (r14/r15-validated)
__device__ __forceinline__ void softbar() {
    asm volatile("s_waitcnt lgkmcnt(0)" ::: "memory");
    __builtin_amdgcn_s_barrier();
    __builtin_amdgcn_sched_barrier(0);
}

// ---------------- fused logits GEMM + softmax: barrier-free k-loop (r20),
// W converted+swizzled from f32 directly in-block (k_prep fused away).
__global__ __launch_bounds__(256) void k1(const float* __restrict__ F,
    const float* __restrict__ Wg, const float* __restrict__ bias,
    float* __restrict__ S_out, u16* __restrict__ Sbf,
    float* __restrict__ sizes, float* __restrict__ scal) {
    __shared__ __align__(16) u16 Wl[64 * 512];
    __shared__ float red4[4];
    const int tid = threadIdx.x;
    const int row0 = blockIdx.x * 64;
    // stage W: convert f32 -> bf16 with the chunk-local swizzle
    for (int j = tid; j < 32768; j += 256) {
        const int k = j >> 6, c = j & 63;
        Wl[c * 512 + (k ^ ((c & 7) << 3))] = f2bf(Wg[j]);
    }

    const int lane = tid & 63;
    const int wv = __builtin_amdgcn_readfirstlane(tid >> 6);
    const int l15 = lane & 15, lq = lane >> 4;
    f32x4 acc[4];
    #pragma unroll
    for (int tn = 0; tn < 4; tn++)
        #pragma unroll
        for (int e = 0; e < 4; e++) acc[tn][e] = 0.f;
    float sumf2 = 0.f;
    __syncthreads();

    const float* frow = F + (size_t)(row0 + wv * 16 + l15) * 512 + lq * 8;
    for (int k0 = 0; k0 < 512; k0 += 64) {
        #pragma unroll
        for (int kk = 0; kk < 64; kk += 32) {
            const float4 va = *(const float4*)(frow + k0 + kk);
            const float4 vb = *(const float4*)(frow + k0 + kk + 4);
            sumf2 += va.x * va.x + va.y * va.y + va.z * va.z + va.w * va.w +
                     vb.x * vb.x + vb.y * vb.y + vb.z * vb.z + vb.w * vb.w;
            bf16x8 a;
            a[0] = (short)f2bf(va.x); a[1] = (short)f2bf(va.y);
            a[2] = (short)f2bf(va.z); a[3] = (short)f2bf(va.w);
            a[4] = (short)f2bf(vb.x); a[5] = (short)f2bf(vb.y);
            a[6] = (short)f2bf(vb.z); a[7] = (short)f2bf(vb.w);
            #pragma unroll
            for (int tn = 0; tn < 4; tn++) {
                const int bc = tn * 16 + l15;
                bf16x8 b = *(const bf16x8*)&Wl[bc * 512 + ((k0 + kk + lq * 8) ^ ((bc & 7) << 3))];
                acc[tn] = __builtin_amdgcn_mfma_f32_16x16x32_bf16(a, b, acc[tn], 0, 0, 0);
            }
        }
    }

    float bias4[4], szacc[4] = {0.f, 0.f, 0.f, 0.f};
    #pragma unroll
    for (int tn = 0; tn < 4; tn++) bias4[tn] = bias[tn * 16 + l15];
    #pragma unroll
    for (int r2 = 0; r2 < 4; r2++) {
        float L[4];
        #pragma unroll
        for (int tn = 0; tn < 4; tn++) L[tn] = acc[tn][r2] + bias4[tn];
        float mx = fmaxf(fmaxf(L[0], L[1]), fmaxf(L[2], L[3]));
        #pragma unroll
        for (int mm = 1; mm < 16; mm <<= 1) mx = fmaxf(mx, __shfl_xor(mx, mm));
        float e[4], s = 0.f;
        #pragma unroll
        for (int tn = 0; tn < 4; tn++) { e[tn] = __expf(L[tn] - mx); s += e[tn]; }
        #pragma unroll
        for (int mm = 1; mm < 16; mm <<= 1) s += __shfl_xor(s, mm);
        const float inv = 1.f / s;
        const size_t grow = (size_t)(row0 + wv * 16 + lq * 4 + r2);
        #pragma unroll
        for (int tn = 0; tn < 4; tn++) {
            const float svl = e[tn] * inv;
            S_out[grow * 64 + tn * 16 + l15] = svl;
            Sbf[grow * 64 + tn * 16 + l15] = f2bf(svl);
            szacc[tn] += svl;
        }
    }
    #pragma unroll
    for (int tn = 0; tn < 4; tn++) {
        float vs = szacc[tn];
        vs += __shfl_xor(vs, 16);
        vs += __shfl_xor(vs, 32);
        if (lq == 0) atomicAdd(sizes + tn * 16 + l15, vs);
    }
    #pragma unroll
    for (int mm = 1; mm < 64; mm <<= 1) sumf2 += __shfl_xor(sumf2, mm);
    if (lane == 0) red4[wv] = sumf2;
    __syncthreads();
    if (tid == 0) atomicAdd(scal + 1, red4[0] + red4[1] + red4[2] + red4[3]);
}

// ---------------- k_mid: fused sweep + k2m + SS on slice-0 (r19 verbatim).
__global__ __launch_bounds__(512) void k_mid(const int* __restrict__ esrc,
    const int* __restrict__ edst, const float* __restrict__ ev,
    const u16* __restrict__ Sbf, const float* __restrict__ S,
    const float* __restrict__ F, const int E2,
    float* __restrict__ GP8, float* __restrict__ SDS8, float* __restrict__ uv8,
    float* __restrict__ AS64, float* __restrict__ deg64, float* __restrict__ scal,
    float* __restrict__ G, float* __restrict__ SS) {
    __shared__ uint32_t Tl[2][2048];
    __shared__ uint32_t Pl[2][2048];
    __shared__ uint32_t Ql[2][2048];
    __shared__ uint32_t Rl[2][2048];
    __shared__ uint32_t Ss2[2048];
    __shared__ uint32_t Fs2[4096];
    const int tid = threadIdx.x;
    const int lane = tid & 63;
    const int wv8 = __builtin_amdgcn_readfirstlane(tid >> 6);   // 0..7
    const int wv = wv8;
    const int l15 = lane & 15, lq = lane >> 4;
    const int xcd = blockIdx.x & 7;
    float* __restrict__ GPmy = GP8 + (size_t)xcd * 4096;
    float* __restrict__ SDSmy = SDS8 + (size_t)xcd * 4096;
    float* __restrict__ umy = uv8 + (size_t)xcd * 64;

    const bool isP = tid < 256;
    const int st = tid & 255;
    const int p = st >> 3, g = st & 7;
    float vsum = 0.f;
    float uacc[8];
    #pragma unroll
    for (int j = 0; j < 8; j++) uacc[j] = 0.f;
    f32x4 aG[2], aSd[2];
    #pragma unroll
    for (int t = 0; t < 2; t++)
        #pragma unroll
        for (int r = 0; r < 4; r++) { aG[t][r] = 0.f; aSd[t][r] = 0.f; }
    const int ma = 16 * (wv & 3) + l15;
    const int aoff = ma * 32, aswz = SWZ(ma);
    const int nb0r = 32 * (wv >> 2) + l15;
    const int nb1r = nb0r + 16;
    const int b0off = nb0r * 32, b0swz = SWZ(nb0r);
    const int b1off = nb1r * 32, b1swz = SWZ(nb1r);

    const int d0 = (blockIdx.x & 3) * 128;
    const int kblk = blockIdx.x >> 2;
    const bool doSS = (blockIdx.x & 3) == 0;
    const int cwv = wv8 & 3, dh = wv8 >> 2;
    f32x4 acc2[4], aSS[2];
    #pragma unroll
    for (int t8 = 0; t8 < 4; t8++)
        #pragma unroll
        for (int r = 0; r < 4; r++) acc2[t8][r] = 0.f;
    #pragma unroll
    for (int t8 = 0; t8 < 2; t8++)
        #pragma unroll
        for (int r = 0; r < 4; r++) aSS[t8][r] = 0.f;
    const int s_ip = tid >> 3;
    const int s_cs = (tid & 7) * 8;
    const int tF = tid - 256;
    const int f_dg = tF & 31;
    const int f_ipb = tF >> 5;

    const int nch = E2 >> 6;
    const int stride = gridDim.x;
    int ch = blockIdx.x;
    const int sweep_left = (ch < nch) ? ((nch - ch + stride - 1) / stride) : 0;

    int2 ia_c, ib_c, ia_n, ib_n;
    float2 vv_c, vv_n;
    {
        const int e0 = (ch << 6) + 2 * p;
        ia_c = isP ? *(const int2*)&edst[e0] : *(const int2*)&esrc[e0];
        ib_c = isP ? *(const int2*)&esrc[e0] : *(const int2*)&edst[e0];
        vv_c = *(const float2*)&ev[e0];
    }
    u16x8 ra_c = *(const u16x8*)&Sbf[(size_t)ia_c.x * 64 + 8 * g];
    u16x8 rb_c = *(const u16x8*)&Sbf[(size_t)ia_c.y * 64 + 8 * g];
    int chn = ch + stride;
    {
        const int chc = chn < nch ? chn : (nch - 1);
        const int e0 = (chc << 6) + 2 * p;
        ia_n = isP ? *(const int2*)&edst[e0] : *(const int2*)&esrc[e0];
        ib_n = isP ? *(const int2*)&esrc[e0] : *(const int2*)&edst[e0];
        vv_n = *(const float2*)&ev[e0];
    }

    int buf = 0;
    int sw_done = 0, mm_done = 0;
    const int total = sweep_left + 8;
    for (int step = 0; step < total; step++) {
        const bool do_mm = (mm_done < 8) &&
                           ((sw_done >= (mm_done + 1) * 4) || (sw_done == sweep_left));
        if (do_mm) {
            const int i0 = kblk * 512 + mm_done * 64;
            if (isP) {
                const u16x8 r0 = *(const u16x8*)&Sbf[(size_t)(i0 + 2 * s_ip) * 64 + s_cs];
                const u16x8 r1 = *(const u16x8*)&Sbf[(size_t)(i0 + 2 * s_ip + 1) * 64 + s_cs];
                #pragma unroll
                for (int j = 0; j < 8; j++) {
                    const int c = s_cs + j;
                    Ss2[c * 32 + (s_ip ^ SWZ2(c))] =
                        (uint32_t)(u16)r0[j] | ((uint32_t)(u16)r1[j] << 16);
                }
            } else {
                #pragma unroll
                for (int s = 0; s < 4; s++) {
                    const int ip = f_ipb + 8 * s;
                    const float4 a = *(const float4*)(F + (size_t)(i0 + 2 * ip) * 512 + d0 + 4 * f_dg);
                    const float4 b = *(const float4*)(F + (size_t)(i0 + 2 * ip + 1) * 512 + d0 + 4 * f_dg);
                    const float al[4] = {a.x, a.y, a.z, a.w};
                    const float bl[4] = {b.x, b.y, b.z, b.w};
                    #pragma unroll
                    for (int j = 0; j < 4; j++) {
                        const int d = 4 * f_dg + j;
                        Fs2[d * 32 + (ip ^ SWZ2(d))] =
                            (uint32_t)f2bf(al[j]) | ((uint32_t)f2bf(bl[j]) << 16);
                    }
                }
            }
            softbar();
            #pragma unroll
            for (int kk = 0; kk < 64; kk += 32) {
                const int w0 = (kk >> 1) + (lq << 2);
                const int ca = 16 * cwv + l15;
                const bf16x8 afrag = *(const bf16x8*)&Ss2[ca * 32 + (w0 ^ SWZ2(ca))];
                #pragma unroll
                for (int t8r = 0; t8r < 4; t8r++) {
                    const int d = 16 * (4 * dh + t8r) + l15;
                    const bf16x8 bfrag = *(const bf16x8*)&Fs2[d * 32 + (w0 ^ SWZ2(d))];
                    acc2[t8r] = __builtin_amdgcn_mfma_f32_16x16x32_bf16(afrag, bfrag, acc2[t8r], 0, 0, 0);
                }
                if (doSS) {
                    #pragma unroll
                    for (int t8r = 0; t8r < 2; t8r++) {
                        const int cb = 16 * (2 * dh + t8r) + l15;
                        const bf16x8 bS = *(const bf16x8*)&Ss2[cb * 32 + (w0 ^ SWZ2(cb))];
                        aSS[t8r] = __builtin_amdgcn_mfma_f32_16x16x32_bf16(afrag, bS, aSS[t8r], 0, 0, 0);
                    }
                }
            }
            softbar();
            mm_done++;
        } else {
            if (isP) {
                #pragma unroll
                for (int j = 0; j < 8; j++) {
                    const int c = 8 * g + j;
                    const int off = c * 32 + (p ^ SWZ(c));
                    Tl[buf][off] = (uint32_t)(u16)ra_c[j] | ((uint32_t)(u16)rb_c[j] << 16);
                    Pl[buf][off] = (uint32_t)f2bf(vv_c.x * bf2f((u16)ra_c[j])) |
                                   ((uint32_t)f2bf(vv_c.y * bf2f((u16)rb_c[j])) << 16);
                }
            } else {
                #pragma unroll
                for (int j = 0; j < 8; j++) {
                    const int c = 8 * g + j;
                    const int off = c * 32 + (p ^ SWZ(c));
                    Ql[buf][off] = (uint32_t)(u16)ra_c[j] | ((uint32_t)(u16)rb_c[j] << 16);
                    Rl[buf][off] = (uint32_t)f2bf(vv_c.x * bf2f((u16)ra_c[j])) |
                                   ((uint32_t)f2bf(vv_c.y * bf2f((u16)rb_c[j])) << 16);
                }
            }
            #pragma unroll
            for (int j = 0; j < 8; j++)
                uacc[j] = fmaf(vv_c.x, bf2f((u16)ra_c[j]),
                          fmaf(vv_c.y, bf2f((u16)rb_c[j]), uacc[j]));
            if (!isP && g == 0) vsum += vv_c.x + vv_c.y;
            if (g == 0) {
                if (ib_c.x < 64) atomicAdd(deg64 + ib_c.x, vv_c.x);
                if (ib_c.y < 64) atomicAdd(deg64 + ib_c.y, vv_c.y);
            }
            if (ib_c.x < 64) {
                const float4 fa = *(const float4*)(S + (size_t)ia_c.x * 64 + 8 * g);
                const float4 fb = *(const float4*)(S + (size_t)ia_c.x * 64 + 8 * g + 4);
                float* dst = AS64 + ib_c.x * 64 + 8 * g;
                atomicAdd(dst + 0, vv_c.x * fa.x); atomicAdd(dst + 1, vv_c.x * fa.y);
                atomicAdd(dst + 2, vv_c.x * fa.z); atomicAdd(dst + 3, vv_c.x * fa.w);
                atomicAdd(dst + 4, vv_c.x * fb.x); atomicAdd(dst + 5, vv_c.x * fb.y);
                atomicAdd(dst + 6, vv_c.x * fb.z); atomicAdd(dst + 7, vv_c.x * fb.w);
            }
            if (ib_c.y < 64) {
                const float4 fa = *(const float4*)(S + (size_t)ia_c.y * 64 + 8 * g);
                const float4 fb = *(const float4*)(S + (size_t)ia_c.y * 64 + 8 * g + 4);
                float* dst = AS64 + ib_c.y * 64 + 8 * g;
                atomicAdd(dst + 0, vv_c.y * fa.x); atomicAdd(dst + 1, vv_c.y * fa.y);
                atomicAdd(dst + 2, vv_c.y * fa.z); atomicAdd(dst + 3, vv_c.y * fa.w);
                atomicAdd(dst + 4, vv_c.y * fb.x); atomicAdd(dst + 5, vv_c.y * fb.y);
                atomicAdd(dst + 6, vv_c.y * fb.z); atomicAdd(dst + 7, vv_c.y * fb.w);
            }
            const u16x8 ra_n = *(const u16x8*)&Sbf[(size_t)ia_n.x * 64 + 8 * g];
            const u16x8 rb_n = *(const u16x8*)&Sbf[(size_t)ia_n.y * 64 + 8 * g];
            const int chnn = chn + stride;
            int2 ia_nn, ib_nn;
            float2 vv_nn;
            {
                const int chc = chnn < nch ? chnn : (nch - 1);
                const int e0 = (chc << 6) + 2 * p;
                ia_nn = isP ? *(const int2*)&edst[e0] : *(const int2*)&esrc[e0];
                ib_nn = isP ? *(const int2*)&esrc[e0] : *(const int2*)&edst[e0];
                vv_nn = *(const float2*)&ev[e0];
            }
            softbar();
            #pragma unroll
            for (int half = 0; half < 2; half++) {
                const int w0 = half * 16 + lq * 4;
                const bf16x8 afP = *(const bf16x8*)&Pl[buf][aoff + (w0 ^ aswz)];
                const bf16x8 afR = *(const bf16x8*)&Rl[buf][aoff + (w0 ^ aswz)];
                const bf16x8 qb0 = *(const bf16x8*)&Ql[buf][b0off + (w0 ^ b0swz)];
                const bf16x8 qb1 = *(const bf16x8*)&Ql[buf][b1off + (w0 ^ b1swz)];
                const bf16x8 tb0 = *(const bf16x8*)&Tl[buf][b0off + (w0 ^ b0swz)];
                const bf16x8 tb1 = *(const bf16x8*)&Tl[buf][b1off + (w0 ^ b1swz)];
                aG[0] = __builtin_amdgcn_mfma_f32_16x16x32_bf16(afP, qb0, aG[0], 0, 0, 0);
                aG[1] = __builtin_amdgcn_mfma_f32_16x16x32_bf16(afP, qb1, aG[1], 0, 0, 0);
                aSd[0] = __builtin_amdgcn_mfma_f32_16x16x32_bf16(afR, qb0, aSd[0], 0, 0, 0);
                aSd[1] = __builtin_amdgcn_mfma_f32_16x16x32_bf16(afR, qb1, aSd[1], 0, 0, 0);
                aSd[0] = __builtin_amdgcn_mfma_f32_16x16x32_bf16(afP, tb0, aSd[0], 0, 0, 0);
                aSd[1] = __builtin_amdgcn_mfma_f32_16x16x32_bf16(afP, tb1, aSd[1], 0, 0, 0);
            }
            ch = chn;
            ia_c = ia_n; ib_c = ib_n; vv_c = vv_n; ra_c = ra_n; rb_c = rb_n;
            ia_n = ia_nn; ib_n = ib_nn; vv_n = vv_nn;
            chn = chnn;
            buf ^= 1;
            sw_done++;
        }
    }
    #pragma unroll
    for (int t = 0; t < 2; t++)
        #pragma unroll
        for (int r = 0; r < 4; r++) {
            const int c1 = 16 * (wv & 3) + 4 * lq + r;
            const int c2 = 32 * (wv >> 2) + 16 * t + l15;
            atomicAdd(GPmy + c1 * 64 + c2, aG[t][r]);
            atomicAdd(SDSmy + c1 * 64 + c2, aSd[t][r]);
        }
    #pragma unroll
    for (int j = 0; j < 8; j++) {
        uacc[j] += __shfl_xor(uacc[j], 8);
        uacc[j] += __shfl_xor(uacc[j], 16);
        uacc[j] += __shfl_xor(uacc[j], 32);
    }
    if (lane < 8) {
        #pragma unroll
        for (int j = 0; j < 8; j++)
            atomicAdd(umy + 8 * lane + j, uacc[j]);
    }
    if (wv >= 4) {
        #pragma unroll
        for (int mm = 1; mm < 64; mm <<= 1) vsum += __shfl_xor(vsum, mm);
        if (lane == 0) atomicAdd(scal + 0, vsum + vsum);   // m = 2*sum(directed v)
    }
    #pragma unroll
    for (int t8r = 0; t8r < 4; t8r++)
        #pragma unroll
        for (int r = 0; r < 4; r++) {
            const int c = 16 * cwv + 4 * lq + r;
            const int d = d0 + 16 * (4 * dh + t8r) + l15;
            atomicAdd(G + (size_t)c * 512 + d, acc2[t8r][r]);
        }
    if (doSS) {
        #pragma unroll
        for (int t8r = 0; t8r < 2; t8r++)
            #pragma unroll
            for (int r = 0; r < 4; r++) {
                const int c = 16 * cwv + 4 * lq + r;
                const int d = 16 * (2 * dh + t8r) + l15;
                atomicAdd(SS + c * 64 + d, aSS[t8r][r]);
            }
    }
}

__device__ __forceinline__ float bred256(float v, float* red) {
    #pragma unroll
    for (int mm = 1; mm < 64; mm <<= 1) v += __shfl_xor(v, mm);
    const int t = threadIdx.x;
    __syncthreads();
    if ((t & 63) == 0) red[t >> 6] = v;
    __syncthreads();
    return red[0] + red[1] + red[2] + red[3];
}

// ---------------- kA: fused merge (GP/SDS/u_vec) + FP=selu(G/sizes) + <G,FP>
__global__ __launch_bounds__(256) void kA(const float* __restrict__ GP8,
    const float* __restrict__ SDS8, const float* __restrict__ uv8,
    float* __restrict__ GP, float* __restrict__ SDS, float* __restrict__ u_vec,
    const float* __restrict__ G, const float* __restrict__ sizes,
    float* __restrict__ FP, float* __restrict__ scal) {
    __shared__ float red[4];
    const int bid = blockIdx.x;
    const int t = threadIdx.x;
    if (bid < 16) {
        const int j = bid * 256 + t;
        const int jt = (j & 63) * 64 + (j >> 6);
        float s = 0.f;
        #pragma unroll
        for (int c = 0; c < 8; c++)
            s += GP8[(size_t)c * 4096 + j] + GP8[(size_t)c * 4096 + jt];
        GP[j] = s;
    } else if (bid < 32) {
        const int j = (bid - 16) * 256 + t;
        float s = 0.f;
        #pragma unroll
        for (int c = 0; c < 8; c++) s += SDS8[(size_t)c * 4096 + j];
        SDS[j] = s;
    } else if (bid == 32) {
        if (t < 64) {
            float s = 0.f;
            #pragma unroll
            for (int c = 0; c < 8; c++) s += uv8[c * 64 + t];
            u_vec[t] = s;
        }
    } else {
        const int idx = (bid - 33) * 256 + t;
        const int c = idx >> 9;
        const float g = G[idx];
        const float x = g / sizes[c];
        const float fp = 1.0507009873554805f * (x > 0.f ? x : 1.6732632423543772f * (__expf(x) - 1.f));
        FP[idx] = fp;
        const float gd = bred256(g * fp, red);
        if (t == 0) atomicAdd(scal + 2, gd);
    }
}

// ---------------- kB: fused FFt = FP FP^T (blocks 0..63) + LU logdet (block 64)
__global__ __launch_bounds__(256) void kB(const float* __restrict__ FP,
    float* __restrict__ FFt, const float* __restrict__ SDS,
    const float* __restrict__ GP, float* __restrict__ scal) {
    __shared__ float redf[256];
    __shared__ float M[64][65];
    __shared__ float red4[4];
    const int tid = threadIdx.x;
    if (blockIdx.x < 64) {
        const int c = blockIdx.x;
        const int cp = tid & 63, part = tid >> 6;
        float a = 0.f;
        const int dbase = part * 128;
        for (int dd = 0; dd < 128; dd++)
            a = fmaf(FP[c * 512 + dbase + dd], FP[cp * 512 + dbase + dd], a);
        redf[tid] = a;
        __syncthreads();
        if (tid < 64)
            FFt[c * 64 + tid] = redf[tid] + redf[tid + 64] + redf[tid + 128] + redf[tid + 192];
    } else {
        const int l = tid & 63, q = tid >> 6;
        #pragma unroll
        for (int j = 0; j < 16; j++) {
            const int c = q * 16 + j;
            M[l][c] = SDS[l * 64 + c] - GP[l * 64 + c] + 1.0f;
        }
        __syncthreads();
        for (int k = 0; k < 63; k++) {
            if (l > k) {
                const float f = M[l][k] / M[k][k];
                const int cend = q * 16 + 16;
                for (int c = (q * 16 > k + 1 ? q * 16 : k + 1); c < cend; c++)
                    M[l][c] = fmaf(-f, M[k][c], M[l][c]);
            }
            __syncthreads();
        }
        float v = (tid < 64) ? logf(fabsf(M[tid][tid])) : 0.f;
        const float ld = bred256(v, red4);
        if (tid == 0) scal[3] = ld;
    }
}

// ---------------- final loss assembly
__global__ __launch_bounds__(256) void k_final(const float* __restrict__ GP,
    const float* __restrict__ SS, const float* __restrict__ FFt, const float* __restrict__ u_vec,
    const float* __restrict__ sizes, const float* __restrict__ deg64,
    const float* __restrict__ AS64, const float* __restrict__ S,
    const float* __restrict__ scal, float* __restrict__ out_loss, const float fn) {
    __shared__ float red[4];
    const int t = threadIdx.x;
    float sA = 0.f, trl = 0.f, trg = 0.f, u2 = 0.f, sz2 = 0.f;
    for (int q = t; q < 4096; q += 256) sA += SS[q] * FFt[q];
    for (int q = t; q < 4096; q += 256) {
        const int i = q >> 6, c = q & 63;
        const float ls = deg64[i] * S[i * 64 + c] - AS64[q];
        trl += ls * FFt[c * 64 + i];
    }
    if (t < 64) { trg = GP[t * 65]; u2 = u_vec[t] * u_vec[t]; sz2 = sizes[t] * sizes[t]; }
    sA = bred256(sA, red);
    trl = bred256(trl, red);
    trg = bred256(trg, red);
    u2 = bred256(u2, red);
    sz2 = bred256(sz2, red);
    if (t == 0) {
        const float m = scal[0], sumF2 = scal[1], gfp = scal[2], lad = scal[3];
        const float spectral = -(trg - u2 / (2.f * m)) / (2.f * m);
        const float collapse = sqrtf(sz2) / fn * 8.f - 1.f;
        const float frob = sqrtf(fmaxf(sA - 2.f * gfp + sumF2, 0.f)) * 1e-4f;
        const float one_two = sqrtf(sz2) * 1e-4f;
        const float smooth = lad * (-1e-4f);
        out_loss[0] = spectral + 0.1f * collapse + smooth + trl + frob + one_two;
    }
}

extern "C" void kernel_launch(void* const* d_in, const int* in_sizes, int n_in,
                              void* d_out, int out_size, void* d_ws, size_t ws_size,
                              hipStream_t stream) {
    const float* F = (const float*)d_in[0];
    const int* esrc = (const int*)d_in[1];
    const int* edst = (const int*)d_in[2];
    const float* ev = (const float*)d_in[3];
    const float* Wg = (const float*)d_in[4];
    const float* bg = (const float*)d_in[5];
    const int n = in_sizes[0] / 512;
    const int E = in_sizes[1];
    const int E2 = E >> 1;   // directed half (list is symmetrized concat)

    float* outF = (float*)d_out;                 // FP [64*512]
    float* outS = outF + 64 * 512;               // S [n*64]
    float* outL = outS + (size_t)n * 64;         // loss scalar

    char* w = (char*)d_ws;
    // ---- zeroed region
    float* sizes = (float*)w;                    // 64
    float* u_vec = sizes + 64;                   // 64
    float* scal = u_vec + 64;                    // 64 (m, sumF2, gfp, logabsdet)
    float* G = scal + 64;                        // 64*512
    float* SS = G + 64 * 512;                    // 4096
    float* AS64 = SS + 4096;                     // 4096
    float* deg64 = AS64 + 4096;                  // 64
    float* GP8 = deg64 + 64;                     // 8*4096
    float* SDS8 = GP8 + 8 * 4096;                // 8*4096
    float* u8buf = SDS8 + 8 * 4096;              // 8*64
    char* zend = (char*)(u8buf + 512);
    const size_t zero_bytes = (size_t)(zend - w);
    // ---- non-zeroed region
    float* GP = (float*)zend;                    // 4096
    float* SDS = GP + 4096;                      // 4096
    float* FFt = SDS + 4096;                     // 4096
    u16* Sbf = (u16*)(FFt + 4096);               // n*64

    hipMemsetAsync(d_ws, 0, zero_bytes, stream);
    k1<<<n / 64, 256, 0, stream>>>(F, Wg, bg, outS, Sbf, sizes, scal);
    k_mid<<<512, 512, 0, stream>>>(esrc, edst, ev, Sbf, outS, F, E2,
                                   GP8, SDS8, u8buf, AS64, deg64, scal, G, SS);
    kA<<<161, 256, 0, stream>>>(GP8, SDS8, u8buf, GP, SDS, u_vec, G, sizes, outF, scal);
    kB<<<65, 256, 0, stream>>>(outF, FFt, SDS, GP, scal);
    k_final<<<1, 256, 0, stream>>>(GP, SS, FFt, u_vec, sizes, deg64, AS64, outS, scal, outL, (float)n);
}

// Round 23
// 427.450 us; speedup vs baseline: 1.0093x; 1.0093x over previous
//
#include <hip/hip_runtime.h>
#include <hip/hip_bf16.h>
#include <cstdint>
#include <cstddef>

typedef unsigned short u16;
typedef float f32x4 __attribute__((ext_vector_type(4)));
typedef short bf16x8 __attribute__((ext_vector_type(8)));
typedef unsigned short u16x8 __attribute__((ext_vector_type(8)));

__device__ __forceinline__ u16 f2bf(float f) {
    uint32_t u = __float_as_uint(f);
    u += 0x7fffu + ((u >> 16) & 1u);
    return (u16)(u >> 16);
}
__device__ __forceinline__ float bf2f(u16 h) {
    return __uint_as_float(((uint32_t)h) << 16);
}

// sweep-tile swizzle (validated r11)
#define SWZ(c) ((((c) ^ ((c) >> 3)) & 7) << 2)
// k2m-tile swizzle (validated r3)
#define SWZ2(c) ((((c) >> 2) & 7) << 2)

// drain-free barrier: order LDS, keep vmem in flight (r14/r15-validated)
__device__ __forceinline__ void softbar() {
    asm volatile("s_waitcnt lgkmcnt(0)" ::: "memory");
    __builtin_amdgcn_s_barrier();
    __builtin_amdgcn_sched_barrier(0);
}

// ---------------- W pre-transpose + swizzle
__global__ __launch_bounds__(256) void k_prep(const float* __restrict__ Wg, u16* __restrict__ Wt) {
    int idx = blockIdx.x * 256 + threadIdx.x;   // 32768
    int k = idx >> 6, c = idx & 63;
    int lin = c * 512 + (k ^ ((c & 7) << 3));
    Wt[lin] = f2bf(Wg[idx]);
}

// ---------------- fused logits GEMM + softmax: barrier-free k-loop (r20)
__global__ __launch_bounds__(256) void k1(const float* __restrict__ F,
    const u16* __restrict__ WtG, const float* __restrict__ bias,
    float* __restrict__ S_out, u16* __restrict__ Sbf,
    float* __restrict__ sizes, float* __restrict__ scal) {
    __shared__ __align__(16) u16 Wl[64 * 512];
    __shared__ float red4[4];
    const int tid = threadIdx.x;
    const int row0 = blockIdx.x * 64;
    for (int j = tid; j < 4096; j += 256)
        ((uint4*)Wl)[j] = ((const uint4*)WtG)[j];

    const int lane = tid & 63;
    const int wv = __builtin_amdgcn_readfirstlane(tid >> 6);
    const int l15 = lane & 15, lq = lane >> 4;
    f32x4 acc[4];
    #pragma unroll
    for (int tn = 0; tn < 4; tn++)
        #pragma unroll
        for (int e = 0; e < 4; e++) acc[tn][e] = 0.f;
    float sumf2 = 0.f;
    __syncthreads();

    const float* frow = F + (size_t)(row0 + wv * 16 + l15) * 512 + lq * 8;
    for (int k0 = 0; k0 < 512; k0 += 64) {
        #pragma unroll
        for (int kk = 0; kk < 64; kk += 32) {
            const float4 va = *(const float4*)(frow + k0 + kk);
            const float4 vb = *(const float4*)(frow + k0 + kk + 4);
            sumf2 += va.x * va.x + va.y * va.y + va.z * va.z + va.w * va.w +
                     vb.x * vb.x + vb.y * vb.y + vb.z * vb.z + vb.w * vb.w;
            bf16x8 a;
            a[0] = (short)f2bf(va.x); a[1] = (short)f2bf(va.y);
            a[2] = (short)f2bf(va.z); a[3] = (short)f2bf(va.w);
            a[4] = (short)f2bf(vb.x); a[5] = (short)f2bf(vb.y);
            a[6] = (short)f2bf(vb.z); a[7] = (short)f2bf(vb.w);
            #pragma unroll
            for (int tn = 0; tn < 4; tn++) {
                const int bc = tn * 16 + l15;
                bf16x8 b = *(const bf16x8*)&Wl[bc * 512 + ((k0 + kk + lq * 8) ^ ((bc & 7) << 3))];
                acc[tn] = __builtin_amdgcn_mfma_f32_16x16x32_bf16(a, b, acc[tn], 0, 0, 0);
            }
        }
    }

    float bias4[4], szacc[4] = {0.f, 0.f, 0.f, 0.f};
    #pragma unroll
    for (int tn = 0; tn < 4; tn++) bias4[tn] = bias[tn * 16 + l15];
    #pragma unroll
    for (int r2 = 0; r2 < 4; r2++) {
        float L[4];
        #pragma unroll
        for (int tn = 0; tn < 4; tn++) L[tn] = acc[tn][r2] + bias4[tn];
        float mx = fmaxf(fmaxf(L[0], L[1]), fmaxf(L[2], L[3]));
        #pragma unroll
        for (int mm = 1; mm < 16; mm <<= 1) mx = fmaxf(mx, __shfl_xor(mx, mm));
        float e[4], s = 0.f;
        #pragma unroll
        for (int tn = 0; tn < 4; tn++) { e[tn] = __expf(L[tn] - mx); s += e[tn]; }
        #pragma unroll
        for (int mm = 1; mm < 16; mm <<= 1) s += __shfl_xor(s, mm);
        const float inv = 1.f / s;
        const size_t grow = (size_t)(row0 + wv * 16 + lq * 4 + r2);
        #pragma unroll
        for (int tn = 0; tn < 4; tn++) {
            const float svl = e[tn] * inv;
            S_out[grow * 64 + tn * 16 + l15] = svl;
            Sbf[grow * 64 + tn * 16 + l15] = f2bf(svl);
            szacc[tn] += svl;
        }
    }
    #pragma unroll
    for (int tn = 0; tn < 4; tn++) {
        float vs = szacc[tn];
        vs += __shfl_xor(vs, 16);
        vs += __shfl_xor(vs, 32);
        if (lq == 0) atomicAdd(sizes + tn * 16 + l15, vs);
    }
    #pragma unroll
    for (int mm = 1; mm < 64; mm <<= 1) sumf2 += __shfl_xor(sumf2, mm);
    if (lane == 0) red4[wv] = sumf2;
    __syncthreads();
    if (tid == 0) atomicAdd(scal + 1, red4[0] + red4[1] + red4[2] + red4[3]);
}

// ---------------- k_mid: fused sweep + k2m + SS on slice-0 (r19 verbatim).
__global__ __launch_bounds__(512) void k_mid(const int* __restrict__ esrc,
    const int* __restrict__ edst, const float* __restrict__ ev,
    const u16* __restrict__ Sbf, const float* __restrict__ S,
    const float* __restrict__ F, const int E2,
    float* __restrict__ GP8, float* __restrict__ SDS8, float* __restrict__ uv8,
    float* __restrict__ AS64, float* __restrict__ deg64, float* __restrict__ scal,
    float* __restrict__ G, float* __restrict__ SS) {
    __shared__ uint32_t Tl[2][2048];
    __shared__ uint32_t Pl[2][2048];
    __shared__ uint32_t Ql[2][2048];
    __shared__ uint32_t Rl[2][2048];
    __shared__ uint32_t Ss2[2048];
    __shared__ uint32_t Fs2[4096];
    const int tid = threadIdx.x;
    const int lane = tid & 63;
    const int wv8 = __builtin_amdgcn_readfirstlane(tid >> 6);   // 0..7
    const int wv = wv8;
    const int l15 = lane & 15, lq = lane >> 4;
    const int xcd = blockIdx.x & 7;
    float* __restrict__ GPmy = GP8 + (size_t)xcd * 4096;
    float* __restrict__ SDSmy = SDS8 + (size_t)xcd * 4096;
    float* __restrict__ umy = uv8 + (size_t)xcd * 64;

    const bool isP = tid < 256;
    const int st = tid & 255;
    const int p = st >> 3, g = st & 7;
    float vsum = 0.f;
    float uacc[8];
    #pragma unroll
    for (int j = 0; j < 8; j++) uacc[j] = 0.f;
    f32x4 aG[2], aSd[2];
    #pragma unroll
    for (int t = 0; t < 2; t++)
        #pragma unroll
        for (int r = 0; r < 4; r++) { aG[t][r] = 0.f; aSd[t][r] = 0.f; }
    const int ma = 16 * (wv & 3) + l15;
    const int aoff = ma * 32, aswz = SWZ(ma);
    const int nb0r = 32 * (wv >> 2) + l15;
    const int nb1r = nb0r + 16;
    const int b0off = nb0r * 32, b0swz = SWZ(nb0r);
    const int b1off = nb1r * 32, b1swz = SWZ(nb1r);

    const int d0 = (blockIdx.x & 3) * 128;
    const int kblk = blockIdx.x >> 2;
    const bool doSS = (blockIdx.x & 3) == 0;
    const int cwv = wv8 & 3, dh = wv8 >> 2;
    f32x4 acc2[4], aSS[2];
    #pragma unroll
    for (int t8 = 0; t8 < 4; t8++)
        #pragma unroll
        for (int r = 0; r < 4; r++) acc2[t8][r] = 0.f;
    #pragma unroll
    for (int t8 = 0; t8 < 2; t8++)
        #pragma unroll
        for (int r = 0; r < 4; r++) aSS[t8][r] = 0.f;
    const int s_ip = tid >> 3;
    const int s_cs = (tid & 7) * 8;
    const int tF = tid - 256;
    const int f_dg = tF & 31;
    const int f_ipb = tF >> 5;

    const int nch = E2 >> 6;
    const int stride = gridDim.x;
    int ch = blockIdx.x;
    const int sweep_left = (ch < nch) ? ((nch - ch + stride - 1) / stride) : 0;

    int2 ia_c, ib_c, ia_n, ib_n;
    float2 vv_c, vv_n;
    {
        const int e0 = (ch << 6) + 2 * p;
        ia_c = isP ? *(const int2*)&edst[e0] : *(const int2*)&esrc[e0];
        ib_c = isP ? *(const int2*)&esrc[e0] : *(const int2*)&edst[e0];
        vv_c = *(const float2*)&ev[e0];
    }
    u16x8 ra_c = *(const u16x8*)&Sbf[(size_t)ia_c.x * 64 + 8 * g];
    u16x8 rb_c = *(const u16x8*)&Sbf[(size_t)ia_c.y * 64 + 8 * g];
    int chn = ch + stride;
    {
        const int chc = chn < nch ? chn : (nch - 1);
        const int e0 = (chc << 6) + 2 * p;
        ia_n = isP ? *(const int2*)&edst[e0] : *(const int2*)&esrc[e0];
        ib_n = isP ? *(const int2*)&esrc[e0] : *(const int2*)&edst[e0];
        vv_n = *(const float2*)&ev[e0];
    }

    int buf = 0;
    int sw_done = 0, mm_done = 0;
    const int total = sweep_left + 8;
    for (int step = 0; step < total; step++) {
        const bool do_mm = (mm_done < 8) &&
                           ((sw_done >= (mm_done + 1) * 4) || (sw_done == sweep_left));
        if (do_mm) {
            const int i0 = kblk * 512 + mm_done * 64;
            if (isP) {
                const u16x8 r0 = *(const u16x8*)&Sbf[(size_t)(i0 + 2 * s_ip) * 64 + s_cs];
                const u16x8 r1 = *(const u16x8*)&Sbf[(size_t)(i0 + 2 * s_ip + 1) * 64 + s_cs];
                #pragma unroll
                for (int j = 0; j < 8; j++) {
                    const int c = s_cs + j;
                    Ss2[c * 32 + (s_ip ^ SWZ2(c))] =
                        (uint32_t)(u16)r0[j] | ((uint32_t)(u16)r1[j] << 16);
                }
            } else {
                #pragma unroll
                for (int s = 0; s < 4; s++) {
                    const int ip = f_ipb + 8 * s;
                    const float4 a = *(const float4*)(F + (size_t)(i0 + 2 * ip) * 512 + d0 + 4 * f_dg);
                    const float4 b = *(const float4*)(F + (size_t)(i0 + 2 * ip + 1) * 512 + d0 + 4 * f_dg);
                    const float al[4] = {a.x, a.y, a.z, a.w};
                    const float bl[4] = {b.x, b.y, b.z, b.w};
                    #pragma unroll
                    for (int j = 0; j < 4; j++) {
                        const int d = 4 * f_dg + j;
                        Fs2[d * 32 + (ip ^ SWZ2(d))] =
                            (uint32_t)f2bf(al[j]) | ((uint32_t)f2bf(bl[j]) << 16);
                    }
                }
            }
            softbar();
            #pragma unroll
            for (int kk = 0; kk < 64; kk += 32) {
                const int w0 = (kk >> 1) + (lq << 2);
                const int ca = 16 * cwv + l15;
                const bf16x8 afrag = *(const bf16x8*)&Ss2[ca * 32 + (w0 ^ SWZ2(ca))];
                #pragma unroll
                for (int t8r = 0; t8r < 4; t8r++) {
                    const int d = 16 * (4 * dh + t8r) + l15;
                    const bf16x8 bfrag = *(const bf16x8*)&Fs2[d * 32 + (w0 ^ SWZ2(d))];
                    acc2[t8r] = __builtin_amdgcn_mfma_f32_16x16x32_bf16(afrag, bfrag, acc2[t8r], 0, 0, 0);
                }
                if (doSS) {
                    #pragma unroll
                    for (int t8r = 0; t8r < 2; t8r++) {
                        const int cb = 16 * (2 * dh + t8r) + l15;
                        const bf16x8 bS = *(const bf16x8*)&Ss2[cb * 32 + (w0 ^ SWZ2(cb))];
                        aSS[t8r] = __builtin_amdgcn_mfma_f32_16x16x32_bf16(afrag, bS, aSS[t8r], 0, 0, 0);
                    }
                }
            }
            softbar();
            mm_done++;
        } else {
            if (isP) {
                #pragma unroll
                for (int j = 0; j < 8; j++) {
                    const int c = 8 * g + j;
                    const int off = c * 32 + (p ^ SWZ(c));
                    Tl[buf][off] = (uint32_t)(u16)ra_c[j] | ((uint32_t)(u16)rb_c[j] << 16);
                    Pl[buf][off] = (uint32_t)f2bf(vv_c.x * bf2f((u16)ra_c[j])) |
                                   ((uint32_t)f2bf(vv_c.y * bf2f((u16)rb_c[j])) << 16);
                }
            } else {
                #pragma unroll
                for (int j = 0; j < 8; j++) {
                    const int c = 8 * g + j;
                    const int off = c * 32 + (p ^ SWZ(c));
                    Ql[buf][off] = (uint32_t)(u16)ra_c[j] | ((uint32_t)(u16)rb_c[j] << 16);
                    Rl[buf][off] = (uint32_t)f2bf(vv_c.x * bf2f((u16)ra_c[j])) |
                                   ((uint32_t)f2bf(vv_c.y * bf2f((u16)rb_c[j])) << 16);
                }
            }
            #pragma unroll
            for (int j = 0; j < 8; j++)
                uacc[j] = fmaf(vv_c.x, bf2f((u16)ra_c[j]),
                          fmaf(vv_c.y, bf2f((u16)rb_c[j]), uacc[j]));
            if (!isP && g == 0) vsum += vv_c.x + vv_c.y;
            if (g == 0) {
                if (ib_c.x < 64) atomicAdd(deg64 + ib_c.x, vv_c.x);
                if (ib_c.y < 64) atomicAdd(deg64 + ib_c.y, vv_c.y);
            }
            if (ib_c.x < 64) {
                const float4 fa = *(const float4*)(S + (size_t)ia_c.x * 64 + 8 * g);
                const float4 fb = *(const float4*)(S + (size_t)ia_c.x * 64 + 8 * g + 4);
                float* dst = AS64 + ib_c.x * 64 + 8 * g;
                atomicAdd(dst + 0, vv_c.x * fa.x); atomicAdd(dst + 1, vv_c.x * fa.y);
                atomicAdd(dst + 2, vv_c.x * fa.z); atomicAdd(dst + 3, vv_c.x * fa.w);
                atomicAdd(dst + 4, vv_c.x * fb.x); atomicAdd(dst + 5, vv_c.x * fb.y);
                atomicAdd(dst + 6, vv_c.x * fb.z); atomicAdd(dst + 7, vv_c.x * fb.w);
            }
            if (ib_c.y < 64) {
                const float4 fa = *(const float4*)(S + (size_t)ia_c.y * 64 + 8 * g);
                const float4 fb = *(const float4*)(S + (size_t)ia_c.y * 64 + 8 * g + 4);
                float* dst = AS64 + ib_c.y * 64 + 8 * g;
                atomicAdd(dst + 0, vv_c.y * fa.x); atomicAdd(dst + 1, vv_c.y * fa.y);
                atomicAdd(dst + 2, vv_c.y * fa.z); atomicAdd(dst + 3, vv_c.y * fa.w);
                atomicAdd(dst + 4, vv_c.y * fb.x); atomicAdd(dst + 5, vv_c.y * fb.y);
                atomicAdd(dst + 6, vv_c.y * fb.z); atomicAdd(dst + 7, vv_c.y * fb.w);
            }
            const u16x8 ra_n = *(const u16x8*)&Sbf[(size_t)ia_n.x * 64 + 8 * g];
            const u16x8 rb_n = *(const u16x8*)&Sbf[(size_t)ia_n.y * 64 + 8 * g];
            const int chnn = chn + stride;
            int2 ia_nn, ib_nn;
            float2 vv_nn;
            {
                const int chc = chnn < nch ? chnn : (nch - 1);
                const int e0 = (chc << 6) + 2 * p;
                ia_nn = isP ? *(const int2*)&edst[e0] : *(const int2*)&esrc[e0];
                ib_nn = isP ? *(const int2*)&esrc[e0] : *(const int2*)&edst[e0];
                vv_nn = *(const float2*)&ev[e0];
            }
            softbar();
            #pragma unroll
            for (int half = 0; half < 2; half++) {
                const int w0 = half * 16 + lq * 4;
                const bf16x8 afP = *(const bf16x8*)&Pl[buf][aoff + (w0 ^ aswz)];
                const bf16x8 afR = *(const bf16x8*)&Rl[buf][aoff + (w0 ^ aswz)];
                const bf16x8 qb0 = *(const bf16x8*)&Ql[buf][b0off + (w0 ^ b0swz)];
                const bf16x8 qb1 = *(const bf16x8*)&Ql[buf][b1off + (w0 ^ b1swz)];
                const bf16x8 tb0 = *(const bf16x8*)&Tl[buf][b0off + (w0 ^ b0swz)];
                const bf16x8 tb1 = *(const bf16x8*)&Tl[buf][b1off + (w0 ^ b1swz)];
                aG[0] = __builtin_amdgcn_mfma_f32_16x16x32_bf16(afP, qb0, aG[0], 0, 0, 0);
                aG[1] = __builtin_amdgcn_mfma_f32_16x16x32_bf16(afP, qb1, aG[1], 0, 0, 0);
                aSd[0] = __builtin_amdgcn_mfma_f32_16x16x32_bf16(afR, qb0, aSd[0], 0, 0, 0);
                aSd[1] = __builtin_amdgcn_mfma_f32_16x16x32_bf16(afR, qb1, aSd[1], 0, 0, 0);
                aSd[0] = __builtin_amdgcn_mfma_f32_16x16x32_bf16(afP, tb0, aSd[0], 0, 0, 0);
                aSd[1] = __builtin_amdgcn_mfma_f32_16x16x32_bf16(afP, tb1, aSd[1], 0, 0, 0);
            }
            ch = chn;
            ia_c = ia_n; ib_c = ib_n; vv_c = vv_n; ra_c = ra_n; rb_c = rb_n;
            ia_n = ia_nn; ib_n = ib_nn; vv_n = vv_nn;
            chn = chnn;
            buf ^= 1;
            sw_done++;
        }
    }
    #pragma unroll
    for (int t = 0; t < 2; t++)
        #pragma unroll
        for (int r = 0; r < 4; r++) {
            const int c1 = 16 * (wv & 3) + 4 * lq + r;
            const int c2 = 32 * (wv >> 2) + 16 * t + l15;
            atomicAdd(GPmy + c1 * 64 + c2, aG[t][r]);
            atomicAdd(SDSmy + c1 * 64 + c2, aSd[t][r]);
        }
    #pragma unroll
    for (int j = 0; j < 8; j++) {
        uacc[j] += __shfl_xor(uacc[j], 8);
        uacc[j] += __shfl_xor(uacc[j], 16);
        uacc[j] += __shfl_xor(uacc[j], 32);
    }
    if (lane < 8) {
        #pragma unroll
        for (int j = 0; j < 8; j++)
            atomicAdd(umy + 8 * lane + j, uacc[j]);
    }
    if (wv >= 4) {
        #pragma unroll
        for (int mm = 1; mm < 64; mm <<= 1) vsum += __shfl_xor(vsum, mm);
        if (lane == 0) atomicAdd(scal + 0, vsum + vsum);   // m = 2*sum(directed v)
    }
    #pragma unroll
    for (int t8r = 0; t8r < 4; t8r++)
        #pragma unroll
        for (int r = 0; r < 4; r++) {
            const int c = 16 * cwv + 4 * lq + r;
            const int d = d0 + 16 * (4 * dh + t8r) + l15;
            atomicAdd(G + (size_t)c * 512 + d, acc2[t8r][r]);
        }
    if (doSS) {
        #pragma unroll
        for (int t8r = 0; t8r < 2; t8r++)
            #pragma unroll
            for (int r = 0; r < 4; r++) {
                const int c = 16 * cwv + 4 * lq + r;
                const int d = 16 * (2 * dh + t8r) + l15;
                atomicAdd(SS + c * 64 + d, aSS[t8r][r]);
            }
    }
}

__device__ __forceinline__ float bred256(float v, float* red) {
    #pragma unroll
    for (int mm = 1; mm < 64; mm <<= 1) v += __shfl_xor(v, mm);
    const int t = threadIdx.x;
    __syncthreads();
    if ((t & 63) == 0) red[t >> 6] = v;
    __syncthreads();
    return red[0] + red[1] + red[2] + red[3];
}

// ---------------- kA: fused merge (GP/SDS/u_vec) + FP=selu(G/sizes) + <G,FP>
__global__ __launch_bounds__(256) void kA(const float* __restrict__ GP8,
    const float* __restrict__ SDS8, const float* __restrict__ uv8,
    float* __restrict__ GP, float* __restrict__ SDS, float* __restrict__ u_vec,
    const float* __restrict__ G, const float* __restrict__ sizes,
    float* __restrict__ FP, float* __restrict__ scal) {
    __shared__ float red[4];
    const int bid = blockIdx.x;
    const int t = threadIdx.x;
    if (bid < 16) {
        const int j = bid * 256 + t;
        const int jt = (j & 63) * 64 + (j >> 6);
        float s = 0.f;
        #pragma unroll
        for (int c = 0; c < 8; c++)
            s += GP8[(size_t)c * 4096 + j] + GP8[(size_t)c * 4096 + jt];
        GP[j] = s;
    } else if (bid < 32) {
        const int j = (bid - 16) * 256 + t;
        float s = 0.f;
        #pragma unroll
        for (int c = 0; c < 8; c++) s += SDS8[(size_t)c * 4096 + j];
        SDS[j] = s;
    } else if (bid == 32) {
        if (t < 64) {
            float s = 0.f;
            #pragma unroll
            for (int c = 0; c < 8; c++) s += uv8[c * 64 + t];
            u_vec[t] = s;
        }
    } else {
        const int idx = (bid - 33) * 256 + t;
        const int c = idx >> 9;
        const float g = G[idx];
        const float x = g / sizes[c];
        const float fp = 1.0507009873554805f * (x > 0.f ? x : 1.6732632423543772f * (__expf(x) - 1.f));
        FP[idx] = fp;
        const float gd = bred256(g * fp, red);
        if (t == 0) atomicAdd(scal + 2, gd);
    }
}

// ---------------- kB: fused FFt = FP FP^T (blocks 0..63) + LU logdet (block 64)
__global__ __launch_bounds__(256) void kB(const float* __restrict__ FP,
    float* __restrict__ FFt, const float* __restrict__ SDS,
    const float* __restrict__ GP, float* __restrict__ scal) {
    __shared__ float redf[256];
    __shared__ float M[64][65];
    __shared__ float red4[4];
    const int tid = threadIdx.x;
    if (blockIdx.x < 64) {
        const int c = blockIdx.x;
        const int cp = tid & 63, part = tid >> 6;
        float a = 0.f;
        const int dbase = part * 128;
        for (int dd = 0; dd < 128; dd++)
            a = fmaf(FP[c * 512 + dbase + dd], FP[cp * 512 + dbase + dd], a);
        redf[tid] = a;
        __syncthreads();
        if (tid < 64)
            FFt[c * 64 + tid] = redf[tid] + redf[tid + 64] + redf[tid + 128] + redf[tid + 192];
    } else {
        const int l = tid & 63, q = tid >> 6;
        #pragma unroll
        for (int j = 0; j < 16; j++) {
            const int c = q * 16 + j;
            M[l][c] = SDS[l * 64 + c] - GP[l * 64 + c] + 1.0f;
        }
        __syncthreads();
        for (int k = 0; k < 63; k++) {
            if (l > k) {
                const float f = M[l][k] / M[k][k];
                const int cend = q * 16 + 16;
                for (int c = (q * 16 > k + 1 ? q * 16 : k + 1); c < cend; c++)
                    M[l][c] = fmaf(-f, M[k][c], M[l][c]);
            }
            __syncthreads();
        }
        float v = (tid < 64) ? logf(fabsf(M[tid][tid])) : 0.f;
        const float ld = bred256(v, red4);
        if (tid == 0) scal[3] = ld;
    }
}

// ---------------- final loss assembly
__global__ __launch_bounds__(256) void k_final(const float* __restrict__ GP,
    const float* __restrict__ SS, const float* __restrict__ FFt, const float* __restrict__ u_vec,
    const float* __restrict__ sizes, const float* __restrict__ deg64,
    const float* __restrict__ AS64, const float* __restrict__ S,
    const float* __restrict__ scal, float* __restrict__ out_loss, const float fn) {
    __shared__ float red[4];
    const int t = threadIdx.x;
    float sA = 0.f, trl = 0.f, trg = 0.f, u2 = 0.f, sz2 = 0.f;
    for (int q = t; q < 4096; q += 256) sA += SS[q] * FFt[q];
    for (int q = t; q < 4096; q += 256) {
        const int i = q >> 6, c = q & 63;
        const float ls = deg64[i] * S[i * 64 + c] - AS64[q];
        trl += ls * FFt[c * 64 + i];
    }
    if (t < 64) { trg = GP[t * 65]; u2 = u_vec[t] * u_vec[t]; sz2 = sizes[t] * sizes[t]; }
    sA = bred256(sA, red);
    trl = bred256(trl, red);
    trg = bred256(trg, red);
    u2 = bred256(u2, red);
    sz2 = bred256(sz2, red);
    if (t == 0) {
        const float m = scal[0], sumF2 = scal[1], gfp = scal[2], lad = scal[3];
        const float spectral = -(trg - u2 / (2.f * m)) / (2.f * m);
        const float collapse = sqrtf(sz2) / fn * 8.f - 1.f;
        const float frob = sqrtf(fmaxf(sA - 2.f * gfp + sumF2, 0.f)) * 1e-4f;
        const float one_two = sqrtf(sz2) * 1e-4f;
        const float smooth = lad * (-1e-4f);
        out_loss[0] = spectral + 0.1f * collapse + smooth + trl + frob + one_two;
    }
}

extern "C" void kernel_launch(void* const* d_in, const int* in_sizes, int n_in,
                              void* d_out, int out_size, void* d_ws, size_t ws_size,
                              hipStream_t stream) {
    const float* F = (const float*)d_in[0];
    const int* esrc = (const int*)d_in[1];
    const int* edst = (const int*)d_in[2];
    const float* ev = (const float*)d_in[3];
    const float* Wg = (const float*)d_in[4];
    const float* bg = (const float*)d_in[5];
    const int n = in_sizes[0] / 512;
    const int E = in_sizes[1];
    const int E2 = E >> 1;   // directed half (list is symmetrized concat)

    float* outF = (float*)d_out;                 // FP [64*512]
    float* outS = outF + 64 * 512;               // S [n*64]
    float* outL = outS + (size_t)n * 64;         // loss scalar

    char* w = (char*)d_ws;
    // ---- zeroed region
    float* sizes = (float*)w;                    // 64
    float* u_vec = sizes + 64;                   // 64
    float* scal = u_vec + 64;                    // 64 (m, sumF2, gfp, logabsdet)
    float* G = scal + 64;                        // 64*512
    float* SS = G + 64 * 512;                    // 4096
    float* AS64 = SS + 4096;                     // 4096
    float* deg64 = AS64 + 4096;                  // 64
    float* GP8 = deg64 + 64;                     // 8*4096
    float* SDS8 = GP8 + 8 * 4096;                // 8*4096
    float* u8buf = SDS8 + 8 * 4096;              // 8*64
    char* zend = (char*)(u8buf + 512);
    const size_t zero_bytes = (size_t)(zend - w);
    // ---- non-zeroed region
    float* GP = (float*)zend;                    // 4096
    float* SDS = GP + 4096;                      // 4096
    float* FFt = SDS + 4096;                     // 4096
    u16* Sbf = (u16*)(FFt + 4096);               // n*64
    u16* Wt = Sbf + (size_t)n * 64;              // 64*512

    hipMemsetAsync(d_ws, 0, zero_bytes, stream);
    k_prep<<<128, 256, 0, stream>>>(Wg, Wt);
    k1<<<n / 64, 256, 0, stream>>>(F, Wt, bg, outS, Sbf, sizes, scal);
    k_mid<<<512, 512, 0, stream>>>(esrc, edst, ev, Sbf, outS, F, E2,
                                   GP8, SDS8, u8buf, AS64, deg64, scal, G, SS);
    kA<<<161, 256, 0, stream>>>(GP8, SDS8, u8buf, GP, SDS, u_vec, G, sizes, outF, scal);
    kB<<<65, 256, 0, stream>>>(outF, FFt, SDS, GP, scal);
    k_final<<<1, 256, 0, stream>>>(GP, SS, FFt, u_vec, sizes, deg64, AS64, outS, scal, outL, (float)n);
}